// Round 3
// baseline (166.470 us; speedup 1.0000x reference)
//
#include <hip/hip_runtime.h>
#include <hip/hip_fp16.h>

#define DIMN 64
#define NNB 16
#define NREL 33
#define WPB 4          // batch elements (waves) per block, 1 elem per wave
#define XSTR 68        // LDS tile row stride in floats (68%32=4 -> 2-way banks = free)
#define WFRAG_BYTES 16384   // w0 hi/lo fragments region at start of d_ws
#define ATTN_EPS 0.001953125f   // 2^-9: skip hop-2 rows with negligible softmax weight

typedef float        floatx4 __attribute__((ext_vector_type(4)));
typedef short        shortx8 __attribute__((ext_vector_type(8)));
typedef unsigned int uintx2  __attribute__((ext_vector_type(2)));

__device__ __forceinline__ float bcastf(float x, int lane) {
    return __int_as_float(__builtin_amdgcn_readlane(__float_as_int(x), lane));
}

// ---- prep: (a) split W0 into bf16 hi/lo MFMA B-fragments; (b) convert
//      ent_emb fp32 -> fp16 table (halves every gathered row to ONE cache line)
__global__ void prep_kernel(const float* __restrict__ W0, unsigned short* __restrict__ wsp,
                            const float* __restrict__ ent, __half* __restrict__ ent16,
                            long n4)
{
    const long tid = (long)blockIdx.x * blockDim.x + threadIdx.x;
    if (tid < 512) {
        const int l = (int)tid & 63;
        const int t = ((int)tid >> 6) & 3;
        const int ks = (int)tid >> 8;
        const int k0 = ks * 32 + (l >> 4) * 8;
        const int n  = t * 16 + (l & 15);
        const unsigned base = ((unsigned)(ks * 4 + t) * 64 + l) * 8;
        #pragma unroll
        for (int j = 0; j < 8; ++j) {
            const float x = W0[(k0 + j) * DIMN + n];
            const unsigned u  = __float_as_uint(x);
            const unsigned uh = u & 0xFFFF0000u;
            const float lf = x - __uint_as_float(uh);       // exact residual
            wsp[base + j]        = (unsigned short)(u >> 16);
            wsp[4096 + base + j] = (unsigned short)(__float_as_uint(lf) >> 16);
        }
    }
    if (ent16) {
        const long stride = (long)gridDim.x * blockDim.x;
        for (long i = tid; i < n4; i += stride) {           // unit = 4 floats
            const float4 x = ((const float4*)ent)[i];
            union { __half2 h[2]; uintx2 u; } pk;
            pk.h[0] = __floats2half2_rn(x.x, x.y);
            pk.h[1] = __floats2half2_rn(x.z, x.w);
            ((uintx2*)ent16)[i] = pk.u;                     // single 8 B store
        }
    }
}

__device__ __forceinline__ floatx4 cvt4(uintx2 raw) {
    union { unsigned int u; __half2 h; } a, b;
    a.u = raw.x; b.u = raw.y;
    const float2 f01 = __half22float2(a.h);
    const float2 f23 = __half22float2(b.h);
    return (floatx4){f01.x, f01.y, f23.x, f23.y};
}

// Round-9: round-2 structure + attention-threshold gather skip.
// Softmax over 16 neighbors of scores with sigma~8 is near-one-hot; rows whose
// weight < 2^-9 are skipped BEFORE the gather (quad-uniform predicate ->
// v_cmpx/execz elides the whole load, masked lanes issue no memory requests).
template<bool F16>
__global__ __launch_bounds__(64 * WPB, 4)
void kgs_kernel(const int* __restrict__ u, const int* __restrict__ v,
                const int* __restrict__ adj, const int* __restrict__ rel_adj,
                const float* __restrict__ usr_emb, const float* __restrict__ ent_emb,
                const __half* __restrict__ ent16,
                const float* __restrict__ rel_emb,
                const float* __restrict__ W0, const float* __restrict__ b0,
                const float* __restrict__ W1, const float* __restrict__ b1,
                const unsigned short* __restrict__ wsp,
                float* __restrict__ out, int B)
{
    const int tid  = threadIdx.x;
    const int wid  = tid >> 6;
    const int d    = tid & 63;
    const int n16  = d & 15;
    const int quad = d >> 4;
    int b = blockIdx.x * WPB + wid;
    if (b >= B) b = B - 1;

    // all LDS wave-private -> no __syncthreads anywhere
    __shared__ __align__(16) float user_sh[WPB][DIMN];
    __shared__ float ur_sh[WPB][NREL + 3];
    __shared__ __align__(16) float sv_sh[WPB][NNB * XSTR];  // hop-1 sv rows
    __shared__ __align__(16) float gbuf[WPB][NNB * XSTR];   // agg rows, then h1

    const int uu = u[b];
    const int vv = v[b];

    const float user_d = usr_emb[(size_t)uu * DIMN + d];
    const int e1n = adj[vv * NNB + n16];
    const int r1n = rel_adj[vv * NNB + n16];
    float sv0;
    if constexpr (F16) sv0 = __half2float(ent16[(size_t)vv * DIMN + d]);
    else               sv0 = ent_emb[(size_t)vv * DIMN + d];
    user_sh[wid][d] = user_d;

    // ---- sv tile: 4 loads cover all 16 hop-1 rows (split layout)
    floatx4 svv[4];
    #pragma unroll
    for (int q = 0; q < 4; ++q) {
        const int em = __shfl(e1n, 4 * q + quad);           // row id for this lane
        if constexpr (F16)
            svv[q] = cvt4(*(const uintx2*)(ent16 + (size_t)em * DIMN + 4 * n16));
        else
            svv[q] = *(const floatx4*)(ent_emb + (size_t)em * DIMN + 4 * n16);
    }

    // ---- index prefetch for hop-2
    int e2n_r[NNB], r2n_r[NNB];
    #pragma unroll
    for (int m = 0; m < NNB; ++m) {
        const int em = __builtin_amdgcn_readlane(e1n, m);
        e2n_r[m] = adj[em * NNB + n16];
        r2n_r[m] = rel_adj[em * NNB + n16];
    }

    // ---- ur table: 33 user-rel dots (wave-private, same-wave LDS)
    if (d < NREL) {
        const float* re = rel_emb + d * DIMN;
        float acc = 0.f;
        #pragma unroll
        for (int k = 0; k < DIMN; k += 4) {
            const float4 uk = *(const float4*)(&user_sh[wid][k]);
            const float4 rk = *(const float4*)(re + k);
            acc = fmaf(uk.x, rk.x, acc);
            acc = fmaf(uk.y, rk.y, acc);
            acc = fmaf(uk.z, rk.z, acc);
            acc = fmaf(uk.w, rk.w, acc);
        }
        ur_sh[wid][d] = acc;
    }

    // park sv tile in LDS (b128 writes, 4 rows per instr)
    #pragma unroll
    for (int q = 0; q < 4; ++q)
        *(floatx4*)(&sv_sh[wid][(4 * q + quad) * XSTR + 4 * n16]) = svv[q];

    // ---- softmax attention for all 16 hop-1 groups (lane layout n16)
    float attn[NNB];
    #pragma unroll
    for (int m = 0; m < NNB; ++m) {
        const float e = __expf(ur_sh[wid][r2n_r[m]]);
        float s = e;
        s += __shfl_xor(s, 1);
        s += __shfl_xor(s, 2);
        s += __shfl_xor(s, 4);
        s += __shfl_xor(s, 8);
        attn[m] = e * __builtin_amdgcn_rcpf(s);
    }

    // ---- hop-2 gather+aggregate, 2-deep pipeline + threshold gather skip
    floatx4 gA[4], gB[4];
    float awA[4], awB[4];

    auto ISSUE = [&](int m, floatx4* g, float* aw) {
        #pragma unroll
        for (int q = 0; q < 4; ++q) {
            const int src = 4 * q + quad;
            const int en  = __shfl(e2n_r[m], src);          // row id (VGPR)
            aw[q] = __shfl(attn[m], src);                   // weight for that row
            g[q] = (floatx4){0.f, 0.f, 0.f, 0.f};
            if (aw[q] >= ATTN_EPS) {                        // quad-uniform predicate
                if constexpr (F16)
                    g[q] = cvt4(*(const uintx2*)(ent16 + (size_t)en * DIMN + 4 * n16));
                else
                    g[q] = *(const floatx4*)(ent_emb + (size_t)en * DIMN + 4 * n16);
            }
        }
    };
    auto REDUCE = [&](int m, floatx4* g, float* aw) {
        floatx4 acc4 = (floatx4){0.f, 0.f, 0.f, 0.f};
        #pragma unroll
        for (int q = 0; q < 4; ++q) {
            acc4[0] = fmaf(aw[q], g[q][0], acc4[0]);
            acc4[1] = fmaf(aw[q], g[q][1], acc4[1]);
            acc4[2] = fmaf(aw[q], g[q][2], acc4[2]);
            acc4[3] = fmaf(aw[q], g[q][3], acc4[3]);
        }
        #pragma unroll
        for (int c = 0; c < 4; ++c) {                       // reduce over quads
            acc4[c] += __shfl_xor(acc4[c], 16);
            acc4[c] += __shfl_xor(acc4[c], 32);
        }
        if (d < 16)
            *(floatx4*)(&gbuf[wid][m * XSTR + 4 * d]) = acc4;
    };

    ISSUE(0, gA, awA);
    #pragma unroll
    for (int m = 0; m < NNB; ++m) {
        if ((m & 1) == 0) {
            if (m + 1 < NNB) ISSUE(m + 1, gB, awB);
            REDUCE(m, gA, awA);
        } else {
            if (m + 1 < NNB) ISSUE(m + 1, gA, awA);
            REDUCE(m, gB, awB);
        }
    }

    // ---- A-fragments: xs = sv + agg; bf16 hi/lo split
    shortx8 Ahi[2], Alo[2];
    #pragma unroll
    for (int ks = 0; ks < 2; ++ks) {
        const int off = (d & 15) * XSTR + quad * 8 + ks * 32;
        const floatx4 sa = *(const floatx4*)(&sv_sh[wid][off]);
        const floatx4 sb = *(const floatx4*)(&sv_sh[wid][off + 4]);
        const floatx4 ga = *(const floatx4*)(&gbuf[wid][off]);
        const floatx4 gb = *(const floatx4*)(&gbuf[wid][off + 4]);
        unsigned uh[8], ul[8];
        #pragma unroll
        for (int j = 0; j < 8; ++j) {
            const float x = (j < 4) ? (sa[j] + ga[j]) : (sb[j - 4] + gb[j - 4]);
            const unsigned ub = __float_as_uint(x);
            uh[j] = ub & 0xFFFF0000u;
            ul[j] = __float_as_uint(x - __uint_as_float(uh[j]));
        }
        union { int i[4]; shortx8 s; } ch, cl;
        #pragma unroll
        for (int p = 0; p < 4; ++p) {
            ch.i[p] = (int)(uh[2 * p + 1] | (uh[2 * p] >> 16));
            cl.i[p] = (int)((ul[2 * p + 1] & 0xFFFF0000u) | (ul[2 * p] >> 16));
        }
        Ahi[ks] = ch.s;
        Alo[ks] = cl.s;
    }

    // ---- MFMA: O = Xhi*Whi + Xhi*Wlo + Xlo*Whi (fp32-accurate 3-term)
    const shortx8* wf = (const shortx8*)wsp;
    floatx4 acc[4];
    #pragma unroll
    for (int t = 0; t < 4; ++t) acc[t] = (floatx4){0.f, 0.f, 0.f, 0.f};
    #pragma unroll
    for (int t = 0; t < 4; ++t) {
        #pragma unroll
        for (int ks = 0; ks < 2; ++ks) {
            const int f = ks * 4 + t;
            const shortx8 bhi = wf[f * 64 + d];
            const shortx8 blo = wf[512 + f * 64 + d];
            acc[t] = __builtin_amdgcn_mfma_f32_16x16x32_bf16(Ahi[ks], bhi, acc[t], 0, 0, 0);
            acc[t] = __builtin_amdgcn_mfma_f32_16x16x32_bf16(Ahi[ks], blo, acc[t], 0, 0, 0);
            acc[t] = __builtin_amdgcn_mfma_f32_16x16x32_bf16(Alo[ks], bhi, acc[t], 0, 0, 0);
        }
    }

    // ---- bias + sigmoid in D-layout (row=quad*4+reg, col=t*16+n16) -> gbuf (reuse)
    #pragma unroll
    for (int t = 0; t < 4; ++t) {
        const float bv = b0[t * 16 + n16];
        #pragma unroll
        for (int reg = 0; reg < 4; ++reg) {
            const float o = acc[t][reg] + bv;
            const int m = quad * 4 + reg;
            gbuf[wid][m * XSTR + t * 16 + n16] = 1.f / (1.f + __expf(-o));
        }
    }

    // ================= hop-0 (per wave, own elem) =============================
    const float e0 = __expf(ur_sh[wid][r1n]);
    float sum0 = e0;
    sum0 += __shfl_xor(sum0, 1);
    sum0 += __shfl_xor(sum0, 2);
    sum0 += __shfl_xor(sum0, 4);
    sum0 += __shfl_xor(sum0, 8);
    const float attn0 = e0 * __builtin_amdgcn_rcpf(sum0);

    float agg0 = 0.f, agg1 = 0.f;
    #pragma unroll
    for (int n = 0; n < NNB; ++n) {
        const float an = bcastf(attn0, n);
        agg0 = fmaf(an, sv_sh[wid][n * XSTR + d], agg0);
        agg1 = fmaf(an, gbuf[wid][n * XSTR + d], agg1);
    }

    // ---- iter0/hop0: sigmoid((sv0+agg0) @ W0 + b0)
    const float x0 = sv0 + agg0;
    float a0 = 0.f, a1 = 0.f, a2 = 0.f, a3 = 0.f;
    for (int k = 0; k < DIMN; k += 4) {
        const float* wr = W0 + k * DIMN;
        a0 = fmaf(bcastf(x0, k + 0), wr[d], a0);
        a1 = fmaf(bcastf(x0, k + 1), wr[DIMN + d], a1);
        a2 = fmaf(bcastf(x0, k + 2), wr[2 * DIMN + d], a2);
        a3 = fmaf(bcastf(x0, k + 3), wr[3 * DIMN + d], a3);
    }
    const float o0 = b0[d] + ((a0 + a1) + (a2 + a3));
    const float h0 = 1.f / (1.f + __expf(-o0));

    // ---- iter1/hop0: tanh((h0+agg1) @ W1 + b1)
    const float x1 = h0 + agg1;
    float c0 = 0.f, c1 = 0.f, c2 = 0.f, c3 = 0.f;
    for (int k = 0; k < DIMN; k += 4) {
        const float* wr = W1 + k * DIMN;
        c0 = fmaf(bcastf(x1, k + 0), wr[d], c0);
        c1 = fmaf(bcastf(x1, k + 1), wr[DIMN + d], c1);
        c2 = fmaf(bcastf(x1, k + 2), wr[2 * DIMN + d], c2);
        c3 = fmaf(bcastf(x1, k + 3), wr[3 * DIMN + d], c3);
    }
    const float o1 = b1[d] + ((c0 + c1) + (c2 + c3));
    const float item_d = 1.f - 2.f / (1.f + __expf(2.f * o1));  // tanh

    // ---- final: sigmoid(user . item)
    float p = user_d * item_d;
    p += __shfl_xor(p, 1);
    p += __shfl_xor(p, 2);
    p += __shfl_xor(p, 4);
    p += __shfl_xor(p, 8);
    p += __shfl_xor(p, 16);
    p += __shfl_xor(p, 32);
    if (d == 0) out[b] = 1.f / (1.f + __expf(-p));
}

extern "C" void kernel_launch(void* const* d_in, const int* in_sizes, int n_in,
                              void* d_out, int out_size, void* d_ws, size_t ws_size,
                              hipStream_t stream) {
    const int*   u       = (const int*)d_in[0];
    const int*   v       = (const int*)d_in[1];
    const int*   adj     = (const int*)d_in[2];
    const int*   rel_adj = (const int*)d_in[3];
    const float* usr_emb = (const float*)d_in[4];
    const float* ent_emb = (const float*)d_in[5];
    const float* rel_emb = (const float*)d_in[6];
    const float* W0      = (const float*)d_in[7];
    const float* b0      = (const float*)d_in[8];
    const float* W1      = (const float*)d_in[9];
    const float* b1      = (const float*)d_in[10];
    float* out = (float*)d_out;
    unsigned short* wsp = (unsigned short*)d_ws;

    const int B = in_sizes[0];                 // 4096
    const long nent = (long)in_sizes[5];       // ent_emb element count (12.8M)
    const size_t need = (size_t)WFRAG_BYTES + (size_t)nent * sizeof(__half);
    const bool use16 = (ws_size >= need) && ((nent & 3) == 0);
    __half* ent16 = use16 ? (__half*)((char*)d_ws + WFRAG_BYTES) : nullptr;

    const long n4 = nent / 4;
    const int conv_blocks = use16 ? 6400 : 2;
    prep_kernel<<<dim3(conv_blocks), dim3(256), 0, stream>>>(W0, wsp, ent_emb, ent16, n4);

    const int grid = (B + WPB - 1) / WPB;
    if (use16)
        kgs_kernel<true><<<dim3(grid), dim3(64 * WPB), 0, stream>>>(
            u, v, adj, rel_adj, usr_emb, ent_emb, ent16, rel_emb, W0, b0, W1, b1,
            wsp, out, B);
    else
        kgs_kernel<false><<<dim3(grid), dim3(64 * WPB), 0, stream>>>(
            u, v, adj, rel_adj, usr_emb, ent_emb, nullptr, rel_emb, W0, b0, W1, b1,
            wsp, out, B);
}

// Round 4
// 155.604 us; speedup vs baseline: 1.0698x; 1.0698x over previous
//
#include <hip/hip_runtime.h>
#include <hip/hip_fp16.h>

#define DIMN 64
#define NNB 16
#define NREL 33
#define WPB 4          // batch elements (waves) per block, 1 elem per wave
#define XSTR 68        // LDS tile row stride in floats (68%32=4 -> 2-way banks = free)
#define WFRAG_BYTES 16384   // w0 hi/lo fragments region at start of d_ws
#define ATTN_EPS 0.001953125f   // 2^-9: skip hop-2 rows with negligible softmax weight

typedef float        floatx4 __attribute__((ext_vector_type(4)));
typedef short        shortx8 __attribute__((ext_vector_type(8)));
typedef unsigned int uintx2  __attribute__((ext_vector_type(2)));

__device__ __forceinline__ float bcastf(float x, int lane) {
    return __int_as_float(__builtin_amdgcn_readlane(__float_as_int(x), lane));
}

// ---- prep: (a) split W0 into bf16 hi/lo MFMA B-fragments; (b) convert
//      ent_emb fp32 -> fp16 table (halves every gathered row to ONE cache line)
__global__ void prep_kernel(const float* __restrict__ W0, unsigned short* __restrict__ wsp,
                            const float* __restrict__ ent, __half* __restrict__ ent16,
                            long n4)
{
    const long tid = (long)blockIdx.x * blockDim.x + threadIdx.x;
    if (tid < 512) {
        const int l = (int)tid & 63;
        const int t = ((int)tid >> 6) & 3;
        const int ks = (int)tid >> 8;
        const int k0 = ks * 32 + (l >> 4) * 8;
        const int n  = t * 16 + (l & 15);
        const unsigned base = ((unsigned)(ks * 4 + t) * 64 + l) * 8;
        #pragma unroll
        for (int j = 0; j < 8; ++j) {
            const float x = W0[(k0 + j) * DIMN + n];
            const unsigned u  = __float_as_uint(x);
            const unsigned uh = u & 0xFFFF0000u;
            const float lf = x - __uint_as_float(uh);       // exact residual
            wsp[base + j]        = (unsigned short)(u >> 16);
            wsp[4096 + base + j] = (unsigned short)(__float_as_uint(lf) >> 16);
        }
    }
    if (ent16) {
        const long stride = (long)gridDim.x * blockDim.x;
        for (long i = tid; i < n4; i += stride) {           // unit = 4 floats
            const float4 x = ((const float4*)ent)[i];
            union { __half2 h[2]; uintx2 u; } pk;
            pk.h[0] = __floats2half2_rn(x.x, x.y);
            pk.h[1] = __floats2half2_rn(x.z, x.w);
            ((uintx2*)ent16)[i] = pk.u;                     // single 8 B store
        }
    }
}

__device__ __forceinline__ floatx4 cvt4(uintx2 raw) {
    union { unsigned int u; __half2 h; } a, b;
    a.u = raw.x; b.u = raw.y;
    const float2 f01 = __half22float2(a.h);
    const float2 f23 = __half22float2(b.h);
    return (floatx4){f01.x, f01.y, f23.x, f23.y};
}

// Round-10: round-2 structure + BRANCHLESS attention-threshold skip.
// Rows with weight < 2^-9 are redirected to hot dummy row 0 (L1-resident) and
// their weight zeroed -> identical math to round-3's passing version, but the
// loads stay unconditional straight-line code (no exec-mask branches, compiler
// pipelining preserved). Unique-line traffic drops ~3-4x on hop-2.
template<bool F16>
__global__ __launch_bounds__(64 * WPB, 4)
void kgs_kernel(const int* __restrict__ u, const int* __restrict__ v,
                const int* __restrict__ adj, const int* __restrict__ rel_adj,
                const float* __restrict__ usr_emb, const float* __restrict__ ent_emb,
                const __half* __restrict__ ent16,
                const float* __restrict__ rel_emb,
                const float* __restrict__ W0, const float* __restrict__ b0,
                const float* __restrict__ W1, const float* __restrict__ b1,
                const unsigned short* __restrict__ wsp,
                float* __restrict__ out, int B)
{
    const int tid  = threadIdx.x;
    const int wid  = tid >> 6;
    const int d    = tid & 63;
    const int n16  = d & 15;
    const int quad = d >> 4;
    int b = blockIdx.x * WPB + wid;
    if (b >= B) b = B - 1;

    // all LDS wave-private -> no __syncthreads anywhere
    __shared__ __align__(16) float user_sh[WPB][DIMN];
    __shared__ float ur_sh[WPB][NREL + 3];
    __shared__ __align__(16) float sv_sh[WPB][NNB * XSTR];  // hop-1 sv rows
    __shared__ __align__(16) float gbuf[WPB][NNB * XSTR];   // agg rows, then h1

    const int uu = u[b];
    const int vv = v[b];

    const float user_d = usr_emb[(size_t)uu * DIMN + d];
    const int e1n = adj[vv * NNB + n16];
    const int r1n = rel_adj[vv * NNB + n16];
    float sv0;
    if constexpr (F16) sv0 = __half2float(ent16[(size_t)vv * DIMN + d]);
    else               sv0 = ent_emb[(size_t)vv * DIMN + d];
    user_sh[wid][d] = user_d;

    // ---- sv tile: 4 loads cover all 16 hop-1 rows (split layout)
    floatx4 svv[4];
    #pragma unroll
    for (int q = 0; q < 4; ++q) {
        const int em = __shfl(e1n, 4 * q + quad);           // row id for this lane
        if constexpr (F16)
            svv[q] = cvt4(*(const uintx2*)(ent16 + (size_t)em * DIMN + 4 * n16));
        else
            svv[q] = *(const floatx4*)(ent_emb + (size_t)em * DIMN + 4 * n16);
    }

    // ---- index prefetch for hop-2
    int e2n_r[NNB], r2n_r[NNB];
    #pragma unroll
    for (int m = 0; m < NNB; ++m) {
        const int em = __builtin_amdgcn_readlane(e1n, m);
        e2n_r[m] = adj[em * NNB + n16];
        r2n_r[m] = rel_adj[em * NNB + n16];
    }

    // ---- ur table: 33 user-rel dots (wave-private, same-wave LDS)
    if (d < NREL) {
        const float* re = rel_emb + d * DIMN;
        float acc = 0.f;
        #pragma unroll
        for (int k = 0; k < DIMN; k += 4) {
            const float4 uk = *(const float4*)(&user_sh[wid][k]);
            const float4 rk = *(const float4*)(re + k);
            acc = fmaf(uk.x, rk.x, acc);
            acc = fmaf(uk.y, rk.y, acc);
            acc = fmaf(uk.z, rk.z, acc);
            acc = fmaf(uk.w, rk.w, acc);
        }
        ur_sh[wid][d] = acc;
    }

    // park sv tile in LDS (b128 writes, 4 rows per instr)
    #pragma unroll
    for (int q = 0; q < 4; ++q)
        *(floatx4*)(&sv_sh[wid][(4 * q + quad) * XSTR + 4 * n16]) = svv[q];

    // ---- softmax attention for all 16 hop-1 groups (lane layout n16)
    float attn[NNB];
    #pragma unroll
    for (int m = 0; m < NNB; ++m) {
        const float e = __expf(ur_sh[wid][r2n_r[m]]);
        float s = e;
        s += __shfl_xor(s, 1);
        s += __shfl_xor(s, 2);
        s += __shfl_xor(s, 4);
        s += __shfl_xor(s, 8);
        attn[m] = e * __builtin_amdgcn_rcpf(s);
    }

    // ---- hop-2 gather+aggregate, 2-deep pipeline + branchless threshold skip
    floatx4 gA[4], gB[4];
    float awA[4], awB[4];

    auto ISSUE = [&](int m, floatx4* g, float* aw) {
        #pragma unroll
        for (int q = 0; q < 4; ++q) {
            const int src = 4 * q + quad;
            const int en  = __shfl(e2n_r[m], src);          // row id (VGPR)
            const float w = __shfl(attn[m], src);           // weight for that row
            const bool keep = (w >= ATTN_EPS);
            const int ens = keep ? en : 0;                  // dummy hot row 0
            aw[q] = keep ? w : 0.f;                         // exact skip semantics
            if constexpr (F16)
                g[q] = cvt4(*(const uintx2*)(ent16 + (size_t)ens * DIMN + 4 * n16));
            else
                g[q] = *(const floatx4*)(ent_emb + (size_t)ens * DIMN + 4 * n16);
        }
    };
    auto REDUCE = [&](int m, floatx4* g, float* aw) {
        floatx4 acc4 = (floatx4){0.f, 0.f, 0.f, 0.f};
        #pragma unroll
        for (int q = 0; q < 4; ++q) {
            acc4[0] = fmaf(aw[q], g[q][0], acc4[0]);
            acc4[1] = fmaf(aw[q], g[q][1], acc4[1]);
            acc4[2] = fmaf(aw[q], g[q][2], acc4[2]);
            acc4[3] = fmaf(aw[q], g[q][3], acc4[3]);
        }
        #pragma unroll
        for (int c = 0; c < 4; ++c) {                       // reduce over quads
            acc4[c] += __shfl_xor(acc4[c], 16);
            acc4[c] += __shfl_xor(acc4[c], 32);
        }
        if (d < 16)
            *(floatx4*)(&gbuf[wid][m * XSTR + 4 * d]) = acc4;
    };

    ISSUE(0, gA, awA);
    #pragma unroll
    for (int m = 0; m < NNB; ++m) {
        if ((m & 1) == 0) {
            if (m + 1 < NNB) ISSUE(m + 1, gB, awB);
            REDUCE(m, gA, awA);
        } else {
            if (m + 1 < NNB) ISSUE(m + 1, gA, awA);
            REDUCE(m, gB, awB);
        }
    }

    // ---- A-fragments: xs = sv + agg; bf16 hi/lo split
    shortx8 Ahi[2], Alo[2];
    #pragma unroll
    for (int ks = 0; ks < 2; ++ks) {
        const int off = (d & 15) * XSTR + quad * 8 + ks * 32;
        const floatx4 sa = *(const floatx4*)(&sv_sh[wid][off]);
        const floatx4 sb = *(const floatx4*)(&sv_sh[wid][off + 4]);
        const floatx4 ga = *(const floatx4*)(&gbuf[wid][off]);
        const floatx4 gb = *(const floatx4*)(&gbuf[wid][off + 4]);
        unsigned uh[8], ul[8];
        #pragma unroll
        for (int j = 0; j < 8; ++j) {
            const float x = (j < 4) ? (sa[j] + ga[j]) : (sb[j - 4] + gb[j - 4]);
            const unsigned ub = __float_as_uint(x);
            uh[j] = ub & 0xFFFF0000u;
            ul[j] = __float_as_uint(x - __uint_as_float(uh[j]));
        }
        union { int i[4]; shortx8 s; } ch, cl;
        #pragma unroll
        for (int p = 0; p < 4; ++p) {
            ch.i[p] = (int)(uh[2 * p + 1] | (uh[2 * p] >> 16));
            cl.i[p] = (int)((ul[2 * p + 1] & 0xFFFF0000u) | (ul[2 * p] >> 16));
        }
        Ahi[ks] = ch.s;
        Alo[ks] = cl.s;
    }

    // ---- MFMA: O = Xhi*Whi + Xhi*Wlo + Xlo*Whi (fp32-accurate 3-term)
    const shortx8* wf = (const shortx8*)wsp;
    floatx4 acc[4];
    #pragma unroll
    for (int t = 0; t < 4; ++t) acc[t] = (floatx4){0.f, 0.f, 0.f, 0.f};
    #pragma unroll
    for (int t = 0; t < 4; ++t) {
        #pragma unroll
        for (int ks = 0; ks < 2; ++ks) {
            const int f = ks * 4 + t;
            const shortx8 bhi = wf[f * 64 + d];
            const shortx8 blo = wf[512 + f * 64 + d];
            acc[t] = __builtin_amdgcn_mfma_f32_16x16x32_bf16(Ahi[ks], bhi, acc[t], 0, 0, 0);
            acc[t] = __builtin_amdgcn_mfma_f32_16x16x32_bf16(Ahi[ks], blo, acc[t], 0, 0, 0);
            acc[t] = __builtin_amdgcn_mfma_f32_16x16x32_bf16(Alo[ks], bhi, acc[t], 0, 0, 0);
        }
    }

    // ---- bias + sigmoid in D-layout (row=quad*4+reg, col=t*16+n16) -> gbuf (reuse)
    #pragma unroll
    for (int t = 0; t < 4; ++t) {
        const float bv = b0[t * 16 + n16];
        #pragma unroll
        for (int reg = 0; reg < 4; ++reg) {
            const float o = acc[t][reg] + bv;
            const int m = quad * 4 + reg;
            gbuf[wid][m * XSTR + t * 16 + n16] = 1.f / (1.f + __expf(-o));
        }
    }

    // ================= hop-0 (per wave, own elem) =============================
    const float e0 = __expf(ur_sh[wid][r1n]);
    float sum0 = e0;
    sum0 += __shfl_xor(sum0, 1);
    sum0 += __shfl_xor(sum0, 2);
    sum0 += __shfl_xor(sum0, 4);
    sum0 += __shfl_xor(sum0, 8);
    const float attn0 = e0 * __builtin_amdgcn_rcpf(sum0);

    float agg0 = 0.f, agg1 = 0.f;
    #pragma unroll
    for (int n = 0; n < NNB; ++n) {
        const float an = bcastf(attn0, n);
        agg0 = fmaf(an, sv_sh[wid][n * XSTR + d], agg0);
        agg1 = fmaf(an, gbuf[wid][n * XSTR + d], agg1);
    }

    // ---- iter0/hop0: sigmoid((sv0+agg0) @ W0 + b0)
    const float x0 = sv0 + agg0;
    float a0 = 0.f, a1 = 0.f, a2 = 0.f, a3 = 0.f;
    for (int k = 0; k < DIMN; k += 4) {
        const float* wr = W0 + k * DIMN;
        a0 = fmaf(bcastf(x0, k + 0), wr[d], a0);
        a1 = fmaf(bcastf(x0, k + 1), wr[DIMN + d], a1);
        a2 = fmaf(bcastf(x0, k + 2), wr[2 * DIMN + d], a2);
        a3 = fmaf(bcastf(x0, k + 3), wr[3 * DIMN + d], a3);
    }
    const float o0 = b0[d] + ((a0 + a1) + (a2 + a3));
    const float h0 = 1.f / (1.f + __expf(-o0));

    // ---- iter1/hop0: tanh((h0+agg1) @ W1 + b1)
    const float x1 = h0 + agg1;
    float c0 = 0.f, c1 = 0.f, c2 = 0.f, c3 = 0.f;
    for (int k = 0; k < DIMN; k += 4) {
        const float* wr = W1 + k * DIMN;
        c0 = fmaf(bcastf(x1, k + 0), wr[d], c0);
        c1 = fmaf(bcastf(x1, k + 1), wr[DIMN + d], c1);
        c2 = fmaf(bcastf(x1, k + 2), wr[2 * DIMN + d], c2);
        c3 = fmaf(bcastf(x1, k + 3), wr[3 * DIMN + d], c3);
    }
    const float o1 = b1[d] + ((c0 + c1) + (c2 + c3));
    const float item_d = 1.f - 2.f / (1.f + __expf(2.f * o1));  // tanh

    // ---- final: sigmoid(user . item)
    float p = user_d * item_d;
    p += __shfl_xor(p, 1);
    p += __shfl_xor(p, 2);
    p += __shfl_xor(p, 4);
    p += __shfl_xor(p, 8);
    p += __shfl_xor(p, 16);
    p += __shfl_xor(p, 32);
    if (d == 0) out[b] = 1.f / (1.f + __expf(-p));
}

extern "C" void kernel_launch(void* const* d_in, const int* in_sizes, int n_in,
                              void* d_out, int out_size, void* d_ws, size_t ws_size,
                              hipStream_t stream) {
    const int*   u       = (const int*)d_in[0];
    const int*   v       = (const int*)d_in[1];
    const int*   adj     = (const int*)d_in[2];
    const int*   rel_adj = (const int*)d_in[3];
    const float* usr_emb = (const float*)d_in[4];
    const float* ent_emb = (const float*)d_in[5];
    const float* rel_emb = (const float*)d_in[6];
    const float* W0      = (const float*)d_in[7];
    const float* b0      = (const float*)d_in[8];
    const float* W1      = (const float*)d_in[9];
    const float* b1      = (const float*)d_in[10];
    float* out = (float*)d_out;
    unsigned short* wsp = (unsigned short*)d_ws;

    const int B = in_sizes[0];                 // 4096
    const long nent = (long)in_sizes[5];       // ent_emb element count (12.8M)
    const size_t need = (size_t)WFRAG_BYTES + (size_t)nent * sizeof(__half);
    const bool use16 = (ws_size >= need) && ((nent & 3) == 0);
    __half* ent16 = use16 ? (__half*)((char*)d_ws + WFRAG_BYTES) : nullptr;

    const long n4 = nent / 4;
    const int conv_blocks = use16 ? 6400 : 2;
    prep_kernel<<<dim3(conv_blocks), dim3(256), 0, stream>>>(W0, wsp, ent_emb, ent16, n4);

    const int grid = (B + WPB - 1) / WPB;
    if (use16)
        kgs_kernel<true><<<dim3(grid), dim3(64 * WPB), 0, stream>>>(
            u, v, adj, rel_adj, usr_emb, ent_emb, ent16, rel_emb, W0, b0, W1, b1,
            wsp, out, B);
    else
        kgs_kernel<false><<<dim3(grid), dim3(64 * WPB), 0, stream>>>(
            u, v, adj, rel_adj, usr_emb, ent_emb, nullptr, rel_emb, W0, b0, W1, b1,
            wsp, out, B);
}

// Round 5
// 149.428 us; speedup vs baseline: 1.1140x; 1.0413x over previous
//
#include <hip/hip_runtime.h>
#include <hip/hip_fp16.h>

#define DIMN 64
#define NNB 16
#define NREL 33
#define WPB 4          // batch elements (waves) per block, 1 elem per wave
#define XSTR 68        // LDS tile row stride in floats (68%32=4 -> 2-way banks = free)
#define WFRAG_BYTES 16384   // w0 hi/lo fragments region at start of d_ws
#define ATTN_EPS 0.001953125f   // 2^-9: skip hop-2 rows with negligible softmax weight

typedef float        floatx4 __attribute__((ext_vector_type(4)));
typedef short        shortx8 __attribute__((ext_vector_type(8)));
typedef unsigned int uintx2  __attribute__((ext_vector_type(2)));

__device__ __forceinline__ float bcastf(float x, int lane) {
    return __int_as_float(__builtin_amdgcn_readlane(__float_as_int(x), lane));
}

// ---- prep: split W0 into bf16 hi/lo MFMA B-fragments (16 KB). The fp16
// entity-table conversion is GONE: rounds 3+4 proved gather line-traffic is
// not the kgs bottleneck (3x fewer lines = 0 time delta), so paying ~77 MB of
// conversion traffic every iteration (workspace is re-poisoned per call) was
// pure overhead.
__global__ void prep_kernel(const float* __restrict__ W0, unsigned short* __restrict__ wsp)
{
    const int tid = blockIdx.x * blockDim.x + threadIdx.x;
    if (tid < 512) {
        const int l = tid & 63;
        const int t = (tid >> 6) & 3;
        const int ks = tid >> 8;
        const int k0 = ks * 32 + (l >> 4) * 8;
        const int n  = t * 16 + (l & 15);
        const unsigned base = ((unsigned)(ks * 4 + t) * 64 + l) * 8;
        #pragma unroll
        for (int j = 0; j < 8; ++j) {
            const float x = W0[(k0 + j) * DIMN + n];
            const unsigned u  = __float_as_uint(x);
            const unsigned uh = u & 0xFFFF0000u;
            const float lf = x - __uint_as_float(uh);       // exact residual
            wsp[base + j]        = (unsigned short)(u >> 16);
            wsp[4096 + base + j] = (unsigned short)(__float_as_uint(lf) >> 16);
        }
    }
}

// Round-11: round-2 structure + branchless threshold skip, fp32 gathers
// straight from ent_emb (no fp16 table). 1 wave/elem, zero barriers.
__global__ __launch_bounds__(64 * WPB, 4)
void kgs_kernel(const int* __restrict__ u, const int* __restrict__ v,
                const int* __restrict__ adj, const int* __restrict__ rel_adj,
                const float* __restrict__ usr_emb, const float* __restrict__ ent_emb,
                const float* __restrict__ rel_emb,
                const float* __restrict__ W0, const float* __restrict__ b0,
                const float* __restrict__ W1, const float* __restrict__ b1,
                const unsigned short* __restrict__ wsp,
                float* __restrict__ out, int B)
{
    const int tid  = threadIdx.x;
    const int wid  = tid >> 6;
    const int d    = tid & 63;
    const int n16  = d & 15;
    const int quad = d >> 4;
    int b = blockIdx.x * WPB + wid;
    if (b >= B) b = B - 1;

    // all LDS wave-private -> no __syncthreads anywhere
    __shared__ __align__(16) float user_sh[WPB][DIMN];
    __shared__ float ur_sh[WPB][NREL + 3];
    __shared__ __align__(16) float sv_sh[WPB][NNB * XSTR];  // hop-1 sv rows
    __shared__ __align__(16) float gbuf[WPB][NNB * XSTR];   // agg rows, then h1

    const int uu = u[b];
    const int vv = v[b];

    const float user_d = usr_emb[(size_t)uu * DIMN + d];
    const int e1n = adj[vv * NNB + n16];
    const int r1n = rel_adj[vv * NNB + n16];
    const float sv0 = ent_emb[(size_t)vv * DIMN + d];
    user_sh[wid][d] = user_d;

    // ---- sv tile: 4 loads cover all 16 hop-1 rows (split layout)
    floatx4 svv[4];
    #pragma unroll
    for (int q = 0; q < 4; ++q) {
        const int em = __shfl(e1n, 4 * q + quad);           // row id for this lane
        svv[q] = *(const floatx4*)(ent_emb + (size_t)em * DIMN + 4 * n16);
    }

    // ---- index prefetch for hop-2
    int e2n_r[NNB], r2n_r[NNB];
    #pragma unroll
    for (int m = 0; m < NNB; ++m) {
        const int em = __builtin_amdgcn_readlane(e1n, m);
        e2n_r[m] = adj[em * NNB + n16];
        r2n_r[m] = rel_adj[em * NNB + n16];
    }

    // ---- ur table: 33 user-rel dots (wave-private, same-wave LDS)
    if (d < NREL) {
        const float* re = rel_emb + d * DIMN;
        float acc = 0.f;
        #pragma unroll
        for (int k = 0; k < DIMN; k += 4) {
            const float4 uk = *(const float4*)(&user_sh[wid][k]);
            const float4 rk = *(const float4*)(re + k);
            acc = fmaf(uk.x, rk.x, acc);
            acc = fmaf(uk.y, rk.y, acc);
            acc = fmaf(uk.z, rk.z, acc);
            acc = fmaf(uk.w, rk.w, acc);
        }
        ur_sh[wid][d] = acc;
    }

    // park sv tile in LDS (b128 writes, 4 rows per instr)
    #pragma unroll
    for (int q = 0; q < 4; ++q)
        *(floatx4*)(&sv_sh[wid][(4 * q + quad) * XSTR + 4 * n16]) = svv[q];

    // ---- softmax attention for all 16 hop-1 groups (lane layout n16)
    float attn[NNB];
    #pragma unroll
    for (int m = 0; m < NNB; ++m) {
        const float e = __expf(ur_sh[wid][r2n_r[m]]);
        float s = e;
        s += __shfl_xor(s, 1);
        s += __shfl_xor(s, 2);
        s += __shfl_xor(s, 4);
        s += __shfl_xor(s, 8);
        attn[m] = e * __builtin_amdgcn_rcpf(s);
    }

    // ---- hop-2 gather+aggregate, 2-deep pipeline + branchless threshold skip
    floatx4 gA[4], gB[4];
    float awA[4], awB[4];

    auto ISSUE = [&](int m, floatx4* g, float* aw) {
        #pragma unroll
        for (int q = 0; q < 4; ++q) {
            const int src = 4 * q + quad;
            const int en  = __shfl(e2n_r[m], src);          // row id (VGPR)
            const float w = __shfl(attn[m], src);           // weight for that row
            const bool keep = (w >= ATTN_EPS);
            const int ens = keep ? en : 0;                  // dummy hot row 0
            aw[q] = keep ? w : 0.f;                         // exact skip semantics
            g[q] = *(const floatx4*)(ent_emb + (size_t)ens * DIMN + 4 * n16);
        }
    };
    auto REDUCE = [&](int m, floatx4* g, float* aw) {
        floatx4 acc4 = (floatx4){0.f, 0.f, 0.f, 0.f};
        #pragma unroll
        for (int q = 0; q < 4; ++q) {
            acc4[0] = fmaf(aw[q], g[q][0], acc4[0]);
            acc4[1] = fmaf(aw[q], g[q][1], acc4[1]);
            acc4[2] = fmaf(aw[q], g[q][2], acc4[2]);
            acc4[3] = fmaf(aw[q], g[q][3], acc4[3]);
        }
        #pragma unroll
        for (int c = 0; c < 4; ++c) {                       // reduce over quads
            acc4[c] += __shfl_xor(acc4[c], 16);
            acc4[c] += __shfl_xor(acc4[c], 32);
        }
        if (d < 16)
            *(floatx4*)(&gbuf[wid][m * XSTR + 4 * d]) = acc4;
    };

    ISSUE(0, gA, awA);
    #pragma unroll
    for (int m = 0; m < NNB; ++m) {
        if ((m & 1) == 0) {
            if (m + 1 < NNB) ISSUE(m + 1, gB, awB);
            REDUCE(m, gA, awA);
        } else {
            if (m + 1 < NNB) ISSUE(m + 1, gA, awA);
            REDUCE(m, gB, awB);
        }
    }

    // ---- A-fragments: xs = sv + agg; bf16 hi/lo split
    shortx8 Ahi[2], Alo[2];
    #pragma unroll
    for (int ks = 0; ks < 2; ++ks) {
        const int off = (d & 15) * XSTR + quad * 8 + ks * 32;
        const floatx4 sa = *(const floatx4*)(&sv_sh[wid][off]);
        const floatx4 sb = *(const floatx4*)(&sv_sh[wid][off + 4]);
        const floatx4 ga = *(const floatx4*)(&gbuf[wid][off]);
        const floatx4 gb = *(const floatx4*)(&gbuf[wid][off + 4]);
        unsigned uh[8], ul[8];
        #pragma unroll
        for (int j = 0; j < 8; ++j) {
            const float x = (j < 4) ? (sa[j] + ga[j]) : (sb[j - 4] + gb[j - 4]);
            const unsigned ub = __float_as_uint(x);
            uh[j] = ub & 0xFFFF0000u;
            ul[j] = __float_as_uint(x - __uint_as_float(uh[j]));
        }
        union { int i[4]; shortx8 s; } ch, cl;
        #pragma unroll
        for (int p = 0; p < 4; ++p) {
            ch.i[p] = (int)(uh[2 * p + 1] | (uh[2 * p] >> 16));
            cl.i[p] = (int)((ul[2 * p + 1] & 0xFFFF0000u) | (ul[2 * p] >> 16));
        }
        Ahi[ks] = ch.s;
        Alo[ks] = cl.s;
    }

    // ---- MFMA: O = Xhi*Whi + Xhi*Wlo + Xlo*Whi (fp32-accurate 3-term)
    const shortx8* wf = (const shortx8*)wsp;
    floatx4 acc[4];
    #pragma unroll
    for (int t = 0; t < 4; ++t) acc[t] = (floatx4){0.f, 0.f, 0.f, 0.f};
    #pragma unroll
    for (int t = 0; t < 4; ++t) {
        #pragma unroll
        for (int ks = 0; ks < 2; ++ks) {
            const int f = ks * 4 + t;
            const shortx8 bhi = wf[f * 64 + d];
            const shortx8 blo = wf[512 + f * 64 + d];
            acc[t] = __builtin_amdgcn_mfma_f32_16x16x32_bf16(Ahi[ks], bhi, acc[t], 0, 0, 0);
            acc[t] = __builtin_amdgcn_mfma_f32_16x16x32_bf16(Ahi[ks], blo, acc[t], 0, 0, 0);
            acc[t] = __builtin_amdgcn_mfma_f32_16x16x32_bf16(Alo[ks], bhi, acc[t], 0, 0, 0);
        }
    }

    // ---- bias + sigmoid in D-layout (row=quad*4+reg, col=t*16+n16) -> gbuf (reuse)
    #pragma unroll
    for (int t = 0; t < 4; ++t) {
        const float bv = b0[t * 16 + n16];
        #pragma unroll
        for (int reg = 0; reg < 4; ++reg) {
            const float o = acc[t][reg] + bv;
            const int m = quad * 4 + reg;
            gbuf[wid][m * XSTR + t * 16 + n16] = 1.f / (1.f + __expf(-o));
        }
    }

    // ================= hop-0 (per wave, own elem) =============================
    const float e0 = __expf(ur_sh[wid][r1n]);
    float sum0 = e0;
    sum0 += __shfl_xor(sum0, 1);
    sum0 += __shfl_xor(sum0, 2);
    sum0 += __shfl_xor(sum0, 4);
    sum0 += __shfl_xor(sum0, 8);
    const float attn0 = e0 * __builtin_amdgcn_rcpf(sum0);

    float agg0 = 0.f, agg1 = 0.f;
    #pragma unroll
    for (int n = 0; n < NNB; ++n) {
        const float an = bcastf(attn0, n);
        agg0 = fmaf(an, sv_sh[wid][n * XSTR + d], agg0);
        agg1 = fmaf(an, gbuf[wid][n * XSTR + d], agg1);
    }

    // ---- iter0/hop0: sigmoid((sv0+agg0) @ W0 + b0)
    const float x0 = sv0 + agg0;
    float a0 = 0.f, a1 = 0.f, a2 = 0.f, a3 = 0.f;
    for (int k = 0; k < DIMN; k += 4) {
        const float* wr = W0 + k * DIMN;
        a0 = fmaf(bcastf(x0, k + 0), wr[d], a0);
        a1 = fmaf(bcastf(x0, k + 1), wr[DIMN + d], a1);
        a2 = fmaf(bcastf(x0, k + 2), wr[2 * DIMN + d], a2);
        a3 = fmaf(bcastf(x0, k + 3), wr[3 * DIMN + d], a3);
    }
    const float o0 = b0[d] + ((a0 + a1) + (a2 + a3));
    const float h0 = 1.f / (1.f + __expf(-o0));

    // ---- iter1/hop0: tanh((h0+agg1) @ W1 + b1)
    const float x1 = h0 + agg1;
    float c0 = 0.f, c1 = 0.f, c2 = 0.f, c3 = 0.f;
    for (int k = 0; k < DIMN; k += 4) {
        const float* wr = W1 + k * DIMN;
        c0 = fmaf(bcastf(x1, k + 0), wr[d], c0);
        c1 = fmaf(bcastf(x1, k + 1), wr[DIMN + d], c1);
        c2 = fmaf(bcastf(x1, k + 2), wr[2 * DIMN + d], c2);
        c3 = fmaf(bcastf(x1, k + 3), wr[3 * DIMN + d], c3);
    }
    const float o1 = b1[d] + ((c0 + c1) + (c2 + c3));
    const float item_d = 1.f - 2.f / (1.f + __expf(2.f * o1));  // tanh

    // ---- final: sigmoid(user . item)
    float p = user_d * item_d;
    p += __shfl_xor(p, 1);
    p += __shfl_xor(p, 2);
    p += __shfl_xor(p, 4);
    p += __shfl_xor(p, 8);
    p += __shfl_xor(p, 16);
    p += __shfl_xor(p, 32);
    if (d == 0) out[b] = 1.f / (1.f + __expf(-p));
}

extern "C" void kernel_launch(void* const* d_in, const int* in_sizes, int n_in,
                              void* d_out, int out_size, void* d_ws, size_t ws_size,
                              hipStream_t stream) {
    const int*   u       = (const int*)d_in[0];
    const int*   v       = (const int*)d_in[1];
    const int*   adj     = (const int*)d_in[2];
    const int*   rel_adj = (const int*)d_in[3];
    const float* usr_emb = (const float*)d_in[4];
    const float* ent_emb = (const float*)d_in[5];
    const float* rel_emb = (const float*)d_in[6];
    const float* W0      = (const float*)d_in[7];
    const float* b0      = (const float*)d_in[8];
    const float* W1      = (const float*)d_in[9];
    const float* b1      = (const float*)d_in[10];
    float* out = (float*)d_out;
    unsigned short* wsp = (unsigned short*)d_ws;

    const int B = in_sizes[0];                 // 4096

    prep_kernel<<<dim3(2), dim3(256), 0, stream>>>(W0, wsp);

    const int grid = (B + WPB - 1) / WPB;
    kgs_kernel<<<dim3(grid), dim3(64 * WPB), 0, stream>>>(
        u, v, adj, rel_adj, usr_emb, ent_emb, rel_emb, W0, b0, W1, b1,
        wsp, out, B);
}